// Round 1
// baseline (254.003 us; speedup 1.0000x reference)
//
#include <hip/hip_runtime.h>

// ---------------------------------------------------------------------------
// LIPAR attention, MI355X. B=4 N=4096 DIM=768 H=12 DH=64 S=16 M=256 C=48.
// Pipeline: rope table | x->bf16 | W->bf16^T | qkv GEMM (+rotary,+scale)
//           | segmented MFMA attention | output GEMM (+bias).
// ---------------------------------------------------------------------------

typedef float f32x4 __attribute__((ext_vector_type(4)));
typedef short bf16x8 __attribute__((ext_vector_type(8)));

#define DEV static __device__ __forceinline__

DEV short f2bf(float f) {  // RNE float->bf16 (bit pattern in short)
  unsigned u = __float_as_uint(f);
  return (short)((u + 0x7FFFu + ((u >> 16) & 1u)) >> 16);
}

DEV f32x4 fz4() { f32x4 z = {0.f, 0.f, 0.f, 0.f}; return z; }

DEV void gload16(const void* g, void* l) {
  // async global->LDS, 16B per lane; LDS dest = wave-uniform base + lane*16
  __builtin_amdgcn_global_load_lds((const __attribute__((address_space(1))) void*)g,
                                   (__attribute__((address_space(3))) void*)l, 16, 0, 0);
}

// ---------------- rope tables: cos/sin[pos][jm], pos<4096, jm<32 ------------
__global__ void __launch_bounds__(256) k_rope(float* __restrict__ cosT,
                                              float* __restrict__ sinT) {
  int idx = blockIdx.x * 256 + threadIdx.x;          // 131072 total
  int pos = idx >> 5, jm = idx & 31;
  float invf = exp2f(-(float)jm * (13.287712379549449f / 32.0f)); // 10000^(-jm/32)
  float th = (float)pos * invf;
  cosT[idx] = cosf(th);
  sinT[idx] = sinf(th);
}

// ---------------- x (fp32) -> xb (bf16) ------------------------------------
__global__ void __launch_bounds__(256) k_cvtx(const float* __restrict__ x,
                                              short* __restrict__ xb) {
  int i = (blockIdx.x * 256 + threadIdx.x) * 8;
  float4 a = *(const float4*)(x + i);
  float4 b = *(const float4*)(x + i + 4);
  bf16x8 v;
  v[0] = f2bf(a.x); v[1] = f2bf(a.y); v[2] = f2bf(a.z); v[3] = f2bf(a.w);
  v[4] = f2bf(b.x); v[5] = f2bf(b.y); v[6] = f2bf(b.z); v[7] = f2bf(b.w);
  *(bf16x8*)(xb + i) = v;
}

// ---------------- W (768x768 fp32) -> Wt[z][j][k] = bf16(W[k][j]) ----------
__global__ void __launch_bounds__(256) k_transw(const float* __restrict__ Wq,
                                                const float* __restrict__ Wkv,
                                                const float* __restrict__ Wo,
                                                const float* __restrict__ Wo0,
                                                short* __restrict__ Wt) {
  __shared__ float t[64][65];
  int z = blockIdx.z;
  const float* src = (z == 0) ? Wq : (z == 1) ? Wkv : (z == 2) ? Wo : Wo0;
  short* dst = Wt + (size_t)z * (768 * 768);
  int k0 = blockIdx.x * 64, j0 = blockIdx.y * 64;
  int tc = threadIdx.x & 63, tr = threadIdx.x >> 6;
#pragma unroll
  for (int i = 0; i < 16; i++) {
    int r = i * 4 + tr;
    t[tc][r] = src[(size_t)(k0 + r) * 768 + j0 + tc];   // coalesced read
  }
  __syncthreads();
#pragma unroll
  for (int i = 0; i < 16; i++) {
    int r = i * 4 + tr;
    dst[(size_t)(j0 + r) * 768 + k0 + tc] = f2bf(t[r][tc]); // coalesced write
  }
}

// ---------------- QKV GEMM 128x128 tile + fused rotary/scale ---------------
// cb 0..5 -> Q (heads 2cb+wc), cb 6..11 -> KV. Output layout [c][pos][64] bf16.
__global__ void __launch_bounds__(256, 2) k_gemm_qkv(
    const short* __restrict__ xb, const short* __restrict__ Wt,
    const float* __restrict__ cosT, const float* __restrict__ sinT,
    short* __restrict__ Qb, short* __restrict__ KVb) {
  __shared__ short Al[128 * 32];
  __shared__ short Bl[128 * 32];
  int r0 = blockIdx.x * 128;
  int cb = blockIdx.y;
  bool isQ = cb < 6;
  int cbl = isQ ? cb : cb - 6;
  const short* W = Wt + (isQ ? (size_t)0 : (size_t)(768 * 768));
  int j0 = cbl * 128;
  int tid = threadIdx.x, lane = tid & 63, wid = tid >> 6;
  int wr = wid >> 1, wc = wid & 1;
  int l15 = lane & 15, lg = lane >> 4;

  f32x4 acc[4][4];
#pragma unroll
  for (int i = 0; i < 4; i++)
#pragma unroll
    for (int j = 0; j < 4; j++) acc[i][j] = fz4();

  for (int kt = 0; kt < 24; kt++) {
    int k0 = kt * 32;
#pragma unroll
    for (int i = 0; i < 2; i++) {
      int g = i * 256 + tid;
      int row = g >> 2, oct = g & 3;
      gload16(xb + (size_t)(r0 + row) * 768 + k0 + oct * 8, &Al[(i * 256 + wid * 64) * 8]);
      gload16(W + (size_t)(j0 + row) * 768 + k0 + oct * 8, &Bl[(i * 256 + wid * 64) * 8]);
    }
    __syncthreads();
    bf16x8 af[4], bfr[4];
#pragma unroll
    for (int mr = 0; mr < 4; mr++)
      af[mr] = *(const bf16x8*)&Al[(wr * 64 + mr * 16 + l15) * 32 + lg * 8];
#pragma unroll
    for (int nc = 0; nc < 4; nc++)
      bfr[nc] = *(const bf16x8*)&Bl[(wc * 64 + nc * 16 + l15) * 32 + lg * 8];
#pragma unroll
    for (int mr = 0; mr < 4; mr++)
#pragma unroll
      for (int nc = 0; nc < 4; nc++)
        acc[mr][nc] = __builtin_amdgcn_mfma_f32_16x16x32_bf16(af[mr], bfr[nc], acc[mr][nc], 0, 0, 0);
    __syncthreads();
  }

  // epilogue: rotary (cols j and j^32 are acc[nc], acc[nc^2] in same lane)
  int h = 2 * cbl + wc;
  short* Ob = isQ ? Qb : KVb;
  float scl = isQ ? 0.125f : 1.0f;  // DH^-0.5
#pragma unroll
  for (int mr = 0; mr < 4; mr++) {
#pragma unroll
    for (int rg = 0; rg < 4; rg++) {
      int r = r0 + wr * 64 + mr * 16 + lg * 4 + rg;
      int b = r >> 12, pos = r & 4095;
      const float* cT = cosT + pos * 32;
      const float* sT = sinT + pos * 32;
      float c0 = cT[l15], s0 = sT[l15];
      float c1 = cT[16 + l15], s1 = sT[16 + l15];
      float v0 = acc[mr][0][rg], v1 = acc[mr][1][rg];
      float v2 = acc[mr][2][rg], v3 = acc[mr][3][rg];
      size_t base = ((size_t)((b * 12 + h) * 4096 + pos)) * 64 + l15;
      Ob[base]      = f2bf((v0 * c0 - v2 * s0) * scl);  // j<32: x*cos - x[j+32]*sin
      Ob[base + 16] = f2bf((v1 * c1 - v3 * s1) * scl);
      Ob[base + 32] = f2bf((v2 * c0 + v0 * s0) * scl);  // j>=32: x*cos + x[j-32]*sin
      Ob[base + 48] = f2bf((v3 * c1 + v1 * s1) * scl);
    }
  }
}

// ---------------- segmented attention --------------------------------------
// WG: (c, segment s, 64-query block); wave = 16 queries. Keys: seg s-1..s (512)
// or seg 0 only (256). Scores in regs; Vt staged in LDS per 256-key half.
#define STAGE_HALF(KOFF)                                                      \
  {                                                                           \
    _Pragma("unroll") for (int i = 0; i < 8; i++) {                           \
      int g = i * 256 + tid;                                                  \
      int n = g & 255, oct = g >> 8;                                          \
      bf16x8 v = *(const bf16x8*)&KVc[(size_t)(Kbase + (KOFF) + n) * 64 + oct * 8]; \
      _Pragma("unroll") for (int j = 0; j < 8; j++)                           \
          Vt[(oct * 8 + j) * 264 + n] = v[j];                                 \
    }                                                                         \
  }

#define PV_BODY(U, UL)                                                        \
  {                                                                           \
    _Pragma("unroll") for (int _t2 = 0; _t2 < 2; _t2++)                       \
        _Pragma("unroll") for (int _rg = 0; _rg < 4; _rg++)                   \
            P[(lg * 4 + _rg) * 40 + _t2 * 16 + l15] = f2bf(sc[2 * (U) + _t2][_rg]); \
    bf16x8 pf = *(const bf16x8*)&P[l15 * 40 + lg * 8];                        \
    _Pragma("unroll") for (int _vt = 0; _vt < 4; _vt++) {                     \
      bf16x8 vf = *(const bf16x8*)&Vt[(_vt * 16 + l15) * 264 + (UL) * 32 + lg * 8]; \
      oacc[_vt] = __builtin_amdgcn_mfma_f32_16x16x32_bf16(pf, vf, oacc[_vt], 0, 0, 0); \
    }                                                                         \
  }

template <int L>
__global__ void __launch_bounds__(256, 2) k_attn(const short* __restrict__ Qb,
                                                 const short* __restrict__ KVb,
                                                 short* __restrict__ AO) {
  constexpr int NT = L / 16;
  __shared__ short Vt[64 * 264];   // V^T half: [dh][n], padded stride 264
  __shared__ short Pl[4][16 * 40]; // per-wave P bounce tile 16x32, stride 40
  int c = blockIdx.x;
  int s = (L == 256) ? 0 : (int)blockIdx.y + 1;
  int qb = blockIdx.z;
  int tid = threadIdx.x, lane = tid & 63, wid = tid >> 6;
  int l15 = lane & 15, lg = lane >> 4;
  const short* KVc = KVb + (size_t)c * 4096 * 64;
  int Kbase = (L == 256) ? 0 : (s - 1) * 256;

  STAGE_HALF(0)  // overlaps with QK^T below; barrier before PV

  int q0 = s * 256 + qb * 64 + wid * 16;
  const short* Qr = Qb + ((size_t)c * 4096 + q0 + l15) * 64 + lg * 8;
  bf16x8 qf0 = *(const bf16x8*)Qr;
  bf16x8 qf1 = *(const bf16x8*)(Qr + 32);

  f32x4 sc[NT];
#pragma unroll
  for (int kt = 0; kt < NT; kt++) {
    const short* Kp = KVc + (size_t)(Kbase + kt * 16 + l15) * 64 + lg * 8;
    bf16x8 kf0 = *(const bf16x8*)Kp;
    bf16x8 kf1 = *(const bf16x8*)(Kp + 32);
    f32x4 z = fz4();
    z = __builtin_amdgcn_mfma_f32_16x16x32_bf16(qf0, kf0, z, 0, 0, 0);
    z = __builtin_amdgcn_mfma_f32_16x16x32_bf16(qf1, kf1, z, 0, 0, 0);
    sc[kt] = z;  // rows m=(lg*4+reg) = query, col = key l15 (per tile kt)
  }

  // wave-parallel softmax over keys (cols live in 16-lane groups)
  float mx[4] = {-1e30f, -1e30f, -1e30f, -1e30f};
#pragma unroll
  for (int kt = 0; kt < NT; kt++)
#pragma unroll
    for (int r = 0; r < 4; r++) mx[r] = fmaxf(mx[r], sc[kt][r]);
#pragma unroll
  for (int r = 0; r < 4; r++)
#pragma unroll
    for (int off = 8; off > 0; off >>= 1)
      mx[r] = fmaxf(mx[r], __shfl_xor(mx[r], off, 64));
  float sm[4] = {0.f, 0.f, 0.f, 0.f};
#pragma unroll
  for (int kt = 0; kt < NT; kt++)
#pragma unroll
    for (int r = 0; r < 4; r++) {
      float e = __expf(sc[kt][r] - mx[r]);
      sc[kt][r] = e;
      sm[r] += e;
    }
#pragma unroll
  for (int r = 0; r < 4; r++)
#pragma unroll
    for (int off = 8; off > 0; off >>= 1) sm[r] += __shfl_xor(sm[r], off, 64);
  float rinv[4];
#pragma unroll
  for (int r = 0; r < 4; r++) rinv[r] = 1.0f / sm[r];

  f32x4 oacc[4] = {fz4(), fz4(), fz4(), fz4()};
  short* P = Pl[wid];

  __syncthreads();  // Vt half 0 ready
#pragma unroll
  for (int uu = 0; uu < 8; uu++) PV_BODY(uu, uu);

  if constexpr (L == 512) {
    __syncthreads();  // all waves done reading half 0
    STAGE_HALF(256)
    __syncthreads();
#pragma unroll
    for (int uu = 0; uu < 8; uu++) PV_BODY(8 + uu, uu);
  }

  int bq = c / 12, hh = c % 12;
#pragma unroll
  for (int vt = 0; vt < 4; vt++)
#pragma unroll
    for (int r = 0; r < 4; r++) {
      int m = lg * 4 + r;
      size_t row = (size_t)bq * 4096 + q0 + m;
      AO[row * 768 + hh * 64 + vt * 16 + l15] = f2bf(oacc[vt][r] * rinv[r]);
    }
}

// ---------------- output GEMM (+bias), W selected per token range ----------
__global__ void __launch_bounds__(256, 2) k_gemm_out(
    const short* __restrict__ AO, const short* __restrict__ Wt,
    const float* __restrict__ bo, const float* __restrict__ bo0,
    float* __restrict__ out) {
  __shared__ short Al[128 * 32];
  __shared__ short Bl[128 * 32];
  int r0 = blockIdx.x * 128;
  int j0 = blockIdx.y * 128;
  bool o0sel = (r0 & 4095) < 256;  // first 256 tokens of each batch -> Wo0/bo0
  const short* W = Wt + (o0sel ? (size_t)3 : (size_t)2) * (768 * 768);
  const float* bias = o0sel ? bo0 : bo;
  int tid = threadIdx.x, lane = tid & 63, wid = tid >> 6;
  int wr = wid >> 1, wc = wid & 1;
  int l15 = lane & 15, lg = lane >> 4;

  f32x4 acc[4][4];
#pragma unroll
  for (int i = 0; i < 4; i++)
#pragma unroll
    for (int j = 0; j < 4; j++) acc[i][j] = fz4();

  for (int kt = 0; kt < 24; kt++) {
    int k0 = kt * 32;
#pragma unroll
    for (int i = 0; i < 2; i++) {
      int g = i * 256 + tid;
      int row = g >> 2, oct = g & 3;
      gload16(AO + (size_t)(r0 + row) * 768 + k0 + oct * 8, &Al[(i * 256 + wid * 64) * 8]);
      gload16(W + (size_t)(j0 + row) * 768 + k0 + oct * 8, &Bl[(i * 256 + wid * 64) * 8]);
    }
    __syncthreads();
    bf16x8 af[4], bfr[4];
#pragma unroll
    for (int mr = 0; mr < 4; mr++)
      af[mr] = *(const bf16x8*)&Al[(wr * 64 + mr * 16 + l15) * 32 + lg * 8];
#pragma unroll
    for (int nc = 0; nc < 4; nc++)
      bfr[nc] = *(const bf16x8*)&Bl[(wc * 64 + nc * 16 + l15) * 32 + lg * 8];
#pragma unroll
    for (int mr = 0; mr < 4; mr++)
#pragma unroll
      for (int nc = 0; nc < 4; nc++)
        acc[mr][nc] = __builtin_amdgcn_mfma_f32_16x16x32_bf16(af[mr], bfr[nc], acc[mr][nc], 0, 0, 0);
    __syncthreads();
  }

  float bs[4];
#pragma unroll
  for (int nc = 0; nc < 4; nc++) bs[nc] = bias[j0 + wc * 64 + nc * 16 + l15];
#pragma unroll
  for (int mr = 0; mr < 4; mr++)
#pragma unroll
    for (int rg = 0; rg < 4; rg++) {
      size_t r = (size_t)r0 + wr * 64 + mr * 16 + lg * 4 + rg;
      float* op = out + r * 768 + j0 + wc * 64 + l15;
      op[0]  = acc[mr][0][rg] + bs[0];
      op[16] = acc[mr][1][rg] + bs[1];
      op[32] = acc[mr][2][rg] + bs[2];
      op[48] = acc[mr][3][rg] + bs[3];
    }
}

// ---------------------------------------------------------------------------
extern "C" void kernel_launch(void* const* d_in, const int* in_sizes, int n_in,
                              void* d_out, int out_size, void* d_ws, size_t ws_size,
                              hipStream_t stream) {
  (void)in_sizes; (void)n_in; (void)out_size; (void)ws_size;
  const float* x   = (const float*)d_in[0];
  const float* Wq  = (const float*)d_in[1];
  const float* Wkv = (const float*)d_in[2];
  const float* Wo  = (const float*)d_in[3];
  const float* bo  = (const float*)d_in[4];
  const float* Wo0 = (const float*)d_in[5];
  const float* bo0 = (const float*)d_in[6];
  float* out = (float*)d_out;

  char* ws = (char*)d_ws;
  // workspace layout (bytes); AO aliases xb (xb dead after qkv GEMM)
  short* xb   = (short*)(ws + 0);          // 16384*768*2 = 25,165,824
  short* AO   = xb;                        // alias
  short* Wt   = (short*)(ws + 25165824);   // 4 * 768*768*2 = 4,718,592
  short* Qb   = (short*)(ws + 29884416);   // 48*4096*64*2 = 25,165,824
  short* KVb  = (short*)(ws + 55050240);   // 25,165,824
  float* cosT = (float*)(ws + 80216064);   // 4096*32*4 = 524,288
  float* sinT = (float*)(ws + 80740352);   // 524,288   (total ~81.3 MB)

  k_rope<<<512, 256, 0, stream>>>(cosT, sinT);
  k_cvtx<<<6144, 256, 0, stream>>>(x, xb);
  k_transw<<<dim3(12, 12, 4), 256, 0, stream>>>(Wq, Wkv, Wo, Wo0, Wt);
  k_gemm_qkv<<<dim3(128, 12), 256, 0, stream>>>(xb, Wt, cosT, sinT, Qb, KVb);
  k_attn<256><<<dim3(48, 1, 4), 256, 0, stream>>>(Qb, KVb, AO);
  k_attn<512><<<dim3(48, 15, 4), 256, 0, stream>>>(Qb, KVb, AO);
  k_gemm_out<<<dim3(128, 6), 256, 0, stream>>>(AO, Wt, bo, bo0, out);
}